// Round 9
// baseline (270.077 us; speedup 1.0000x reference)
//
#include <hip/hip_runtime.h>

#define BB   16384
#define GENC 216
#define OBS  512
#define NH   1024
#define NC   64
#define NFAC 8
#define NIN  1240
#define KP1  1280   // layer-1 K padded to multiple of 64
#define MTILES 136  // worst-case sum ceil(cnt_f/128)
#define MT256  72   // worst-case sum ceil(cnt_f/256): 64 + 8 partials

typedef __attribute__((ext_vector_type(4))) float f32x4;
typedef __attribute__((ext_vector_type(8))) short short8;
typedef __attribute__((ext_vector_type(4))) short short4v;

__device__ __forceinline__ unsigned short f2bf(float f) {
  union { float f; unsigned u; } x; x.f = f;
  unsigned r = x.u + 0x7fffu + ((x.u >> 16) & 1u);
  return (unsigned short)(r >> 16);
}

__device__ __forceinline__ void gl_lds16(const unsigned short* g, unsigned short* l) {
  __builtin_amdgcn_global_load_lds(
      (const __attribute__((address_space(1))) void*)g,
      (__attribute__((address_space(3))) void*)l, 16, 0, 0);
}

// bijective XCD-chunked swizzle (m204)
__device__ __forceinline__ int xcd_chunk(int gid, int nwg) {
  int q = nwg >> 3, r = nwg & 7, x = gid & 7, p = gid >> 3;
  return (x < r ? x * (q + 1) : r * (q + 1) + (x - r) * q) + p;
}

// ---------- bucket: per-row last-active factor, LDS-aggregated atomics ----------
__global__ void bucket_kernel(const float* __restrict__ graph,
                              int* __restrict__ cnt, int* __restrict__ rowlist) {
  __shared__ int lcnt[NFAC];
  __shared__ int lbase[NFAC];
  int tid = threadIdx.x;
  if (tid < NFAC) lcnt[tid] = 0;
  __syncthreads();
  int b = blockIdx.x * 256 + tid;
  const float* g = graph + (size_t)b * GENC;
  float4 g0 = *(const float4*)g;
  float4 g1 = *(const float4*)(g + 4);
  int f = -1;
  if (g0.x == 1.f) f = 0;
  if (g0.y == 1.f) f = 1;
  if (g0.z == 1.f) f = 2;
  if (g0.w == 1.f) f = 3;
  if (g1.x == 1.f) f = 4;
  if (g1.y == 1.f) f = 5;
  if (g1.z == 1.f) f = 6;
  if (g1.w == 1.f) f = 7;
  int li = 0;
  if (f >= 0) li = atomicAdd(&lcnt[f], 1);
  __syncthreads();
  if (tid < NFAC) lbase[tid] = lcnt[tid] ? atomicAdd(&cnt[tid], lcnt[tid]) : 0;
  __syncthreads();
  if (f >= 0) rowlist[f * BB + lbase[f] + li] = b;
}

// -------- gather active rows (global position), concat + f32->bf16, pad to 1280 --------
__global__ void gather_x(const float* __restrict__ graph,
                         const float* __restrict__ state,
                         const float* __restrict__ nexts,
                         const int* __restrict__ cnt,
                         const int* __restrict__ rowlist,
                         unsigned short* __restrict__ xg) {
  int w = threadIdx.x >> 6, lane = threadIdx.x & 63;
  int pos = blockIdx.x * 4 + w;
  int f = -1, loc = 0, acc = 0;
#pragma unroll
  for (int i = 0; i < NFAC; ++i) {
    int c = cnt[i];
    if (f < 0 && pos < acc + c) { f = i; loc = pos - acc; }
    acc += c;
  }
  if (f < 0) return;
  int b = rowlist[f * BB + loc];
  unsigned short* dst = xg + (size_t)pos * KP1;
#pragma unroll
  for (int it = 0; it < 5; ++it) {
    int c = it * 64 + lane;
    float4 v;
    if (c < 54)       v = *(const float4*)(graph + (size_t)b * GENC + c * 4);
    else if (c < 182) v = *(const float4*)(state + (size_t)b * OBS + (c - 54) * 4);
    else if (c < 310) v = *(const float4*)(nexts + (size_t)b * OBS + (c - 182) * 4);
    else              v = make_float4(0.f, 0.f, 0.f, 0.f);
    short4v s;
    s[0] = (short)f2bf(v.x); s[1] = (short)f2bf(v.y);
    s[2] = (short)f2bf(v.z); s[3] = (short)f2bf(v.w);
    *(short4v*)(dst + c * 4) = s;
  }
}

// ---- merged transpose+convert: f32 [F][K][N] -> bf16 [F][N][KPad] ----
__global__ void transpose_all(const float* __restrict__ W1,
                              const float* __restrict__ W2,
                              const float* __restrict__ W3,
                              unsigned short* __restrict__ w1t,
                              unsigned short* __restrict__ w2t,
                              unsigned short* __restrict__ w3t) {
  __shared__ unsigned short tile[64][65];
  int z = blockIdx.z;
  const float* src; unsigned short* dst; int K, N, KPad;
  if (z < 8)        { src = W1 + (size_t)z * NIN * NH;       dst = w1t + (size_t)z * NH * KP1; K = NIN; N = NH; KPad = KP1; }
  else if (z < 16)  { src = W2 + (size_t)(z - 8) * NH * NH;  dst = w2t + (size_t)(z - 8) * NH * NH; K = NH; N = NH; KPad = NH; }
  else              { src = W3 + (size_t)(z - 16) * NH * NC; dst = w3t + (size_t)(z - 16) * NC * NH; K = NH; N = NC; KPad = NH; }
  int k0 = blockIdx.y * 64, n0 = blockIdx.x * 64;
  if (k0 >= KPad || n0 >= N) return;
  int tr = threadIdx.x >> 6, tc = threadIdx.x & 63;
#pragma unroll
  for (int i = 0; i < 16; ++i) {
    int r = i * 4 + tr;
    int k = k0 + r;
    float v = (k < K) ? src[(size_t)k * N + n0 + tc] : 0.0f;
    tile[r][tc] = f2bf(v);
  }
  __syncthreads();
  int kp = threadIdx.x & 31, nb = threadIdx.x >> 5;
#pragma unroll
  for (int i = 0; i < 8; ++i) {
    int n = i * 8 + nb;
    union { short2 s2; unsigned u; } v;
    v.s2.x = (short)tile[kp * 2][n];
    v.s2.y = (short)tile[kp * 2 + 1][n];
    *(unsigned*)(dst + (size_t)(n0 + n) * KPad + k0 + kp * 2) = v.u;
  }
}

// ======== 256^2-tile, 8-wave, dbuf, counted-vmcnt multi-phase GEMM (L1/L2) ========
// Per K-tile t: phase h0 computes m-frags 0-3 (32 MFMA), h1 computes 4-7.
// Staging units (8KB = 1 gl_lds/thread): A rows u*64 (u=0..3), B cols (u-4)*64.
// h0(t) stages units {0,2,4,5,6,7} of t+1 (A-mq0 + B); h1(t) stages {1,3}.
// Waits: h0 vmcnt(2) [leaves A13(t)], h1 vmcnt(6) [leaves stage6(t+1)], tail 0.
template <int LAYER>
__launch_bounds__(512, 2)
__global__ void mlp_gemm256(const unsigned short* __restrict__ Abase,
                            const unsigned short* __restrict__ Wt,
                            const float* __restrict__ bias,
                            unsigned short* __restrict__ Hout,
                            const int* __restrict__ cnt) {
  constexpr int K  = (LAYER == 1) ? KP1 : NH;
  constexpr int NT = K / 64;
  constexpr int NB = NH / 256;  // 4 n-blocks

  extern __shared__ unsigned short smem[];
  unsigned short* As0 = smem;
  unsigned short* As1 = smem + 16384;
  unsigned short* Bs0 = smem + 32768;
  unsigned short* Bs1 = smem + 49152;

  const int wg = xcd_chunk(blockIdx.x, MT256 * NB);
  const int ty = wg / NB;           // m-tile (n fastest: A-panel L2 reuse)
  const int n0 = (wg % NB) * 256;

  int f = -1, m0 = 0, goff = 0, cntf = 0;
  {
    int acc = 0, off = 0;
#pragma unroll
    for (int i = 0; i < NFAC; ++i) {
      int c = cnt[i];
      int t = (c + 255) >> 8;
      if (f < 0 && ty < acc + t) { f = i; m0 = (ty - acc) * 256; goff = off; cntf = c; }
      acc += t; off += c;
    }
  }
  if (f < 0) return;

  const int tid = threadIdx.x, wid = tid >> 6, lane = tid & 63;
  const int wm = wid >> 2, wn = wid & 3;

  // staging sources: per-lane pre-swizzled (linear LDS dest, swz source)
  const int sr = tid >> 3;              // row within 64-row unit
  const int sc = (tid & 7) ^ (sr & 7);  // swizzled 16B chunk
  const unsigned short* pu[8];
  {
    const unsigned short* Ao = Abase + (size_t)(goff + m0) * K;
    const unsigned short* Bo = Wt + (size_t)f * NH * K + (size_t)n0 * K;
#pragma unroll
    for (int u = 0; u < 4; ++u) pu[u] = Ao + (size_t)(u * 64 + sr) * K + sc * 8;
#pragma unroll
    for (int u = 0; u < 4; ++u) pu[4 + u] = Bo + (size_t)(u * 64 + sr) * K + sc * 8;
  }
  const int ldst = wid * 512;  // wave-uniform LDS elem offset within a unit

  f32x4 acc[8][4];
#pragma unroll
  for (int a = 0; a < 8; ++a)
#pragma unroll
    for (int b = 0; b < 4; ++b) acc[a][b] = (f32x4){0.f, 0.f, 0.f, 0.f};

  auto stage6 = [&](unsigned short* Ab, unsigned short* Bb) {
    gl_lds16(pu[0], Ab + 0 * 4096 + ldst); pu[0] += 64;
    gl_lds16(pu[2], Ab + 2 * 4096 + ldst); pu[2] += 64;
#pragma unroll
    for (int u = 0; u < 4; ++u) { gl_lds16(pu[4 + u], Bb + u * 4096 + ldst); pu[4 + u] += 64; }
  };
  auto stage2 = [&](unsigned short* Ab) {
    gl_lds16(pu[1], Ab + 1 * 4096 + ldst); pu[1] += 64;
    gl_lds16(pu[3], Ab + 3 * 4096 + ldst); pu[3] += 64;
  };

  short8 bfr[4][2];

  // prologue: full K-tile 0 into buf0 (8 loads/thread in flight)
  stage6(As0, Bs0);
  stage2(As0);

#pragma unroll 1
  for (int t = 0; t < NT; ++t) {
    unsigned short* Ab = (t & 1) ? As1 : As0;
    unsigned short* Bb = (t & 1) ? Bs1 : Bs0;
    unsigned short* An = (t & 1) ? As0 : As1;
    unsigned short* Bn = (t & 1) ? Bs0 : Bs1;

    // ---------- phase h0: needs A-mq0(t) + B(t) ----------
    asm volatile("s_waitcnt vmcnt(2)" ::: "memory");
    __builtin_amdgcn_sched_barrier(0);
    __builtin_amdgcn_s_barrier();
    __builtin_amdgcn_sched_barrier(0);
    {
      short8 afr[4][2];
#pragma unroll
      for (int nf = 0; nf < 4; ++nf) {
        int c = wn * 64 + nf * 16 + (lane & 15);
#pragma unroll
        for (int ks = 0; ks < 2; ++ks) {
          int kc = ks * 4 + (lane >> 4);
          bfr[nf][ks] = *(const short8*)(Bb + c * 64 + ((kc ^ (c & 7)) << 3));
        }
      }
#pragma unroll
      for (int mf = 0; mf < 4; ++mf) {
        int r = wm * 128 + mf * 16 + (lane & 15);
#pragma unroll
        for (int ks = 0; ks < 2; ++ks) {
          int kc = ks * 4 + (lane >> 4);
          afr[mf][ks] = *(const short8*)(Ab + r * 64 + ((kc ^ (r & 7)) << 3));
        }
      }
      if (t + 1 < NT) stage6(An, Bn);   // tile t+1: A-mq0 + B -> other buf
      __builtin_amdgcn_s_setprio(1);
#pragma unroll
      for (int mf = 0; mf < 4; ++mf)
#pragma unroll
        for (int nf = 0; nf < 4; ++nf)
#pragma unroll
          for (int ks = 0; ks < 2; ++ks)
            acc[mf][nf] = __builtin_amdgcn_mfma_f32_16x16x32_bf16(
                afr[mf][ks], bfr[nf][ks], acc[mf][nf], 0, 0, 0);
      __builtin_amdgcn_s_setprio(0);
    }

    // ---------- phase h1: needs A-mq1(t) ----------
    if (t + 1 < NT) { asm volatile("s_waitcnt vmcnt(6)" ::: "memory"); }
    else            { asm volatile("s_waitcnt vmcnt(0)" ::: "memory"); }
    __builtin_amdgcn_sched_barrier(0);
    __builtin_amdgcn_s_barrier();
    __builtin_amdgcn_sched_barrier(0);
    {
      short8 afr[4][2];
#pragma unroll
      for (int mf = 0; mf < 4; ++mf) {
        int r = wm * 128 + (mf + 4) * 16 + (lane & 15);
#pragma unroll
        for (int ks = 0; ks < 2; ++ks) {
          int kc = ks * 4 + (lane >> 4);
          afr[mf][ks] = *(const short8*)(Ab + r * 64 + ((kc ^ (r & 7)) << 3));
        }
      }
      if (t + 1 < NT) stage2(An);       // tile t+1: A-mq1
      __builtin_amdgcn_s_setprio(1);
#pragma unroll
      for (int mf = 0; mf < 4; ++mf)
#pragma unroll
        for (int nf = 0; nf < 4; ++nf)
#pragma unroll
          for (int ks = 0; ks < 2; ++ks)
            acc[mf + 4][nf] = __builtin_amdgcn_mfma_f32_16x16x32_bf16(
                afr[mf][ks], bfr[nf][ks], acc[mf + 4][nf], 0, 0, 0);
      __builtin_amdgcn_s_setprio(0);
    }
  }

  // ---- epilogue: bias + relu + bf16 store ----
  const float* bs = bias + f * NH;
#pragma unroll
  for (int nf = 0; nf < 4; ++nf) {
    int col = n0 + wn * 64 + nf * 16 + (lane & 15);
    float bv = bs[col];
#pragma unroll
    for (int mf = 0; mf < 8; ++mf) {
      int rbase = wm * 128 + mf * 16 + ((lane >> 4) << 2);
#pragma unroll
      for (int i = 0; i < 4; ++i) {
        int pos = m0 + rbase + i;
        if (pos < cntf) {
          float v = fmaxf(acc[mf][nf][i] + bv, 0.0f);
          Hout[(size_t)(goff + pos) * NH + col] = f2bf(v);
        }
      }
    }
  }
}

// ------ layer-3 GEMM: depth-2 counted-vmcnt 128x64 (unchanged) ------
template <int LAYER>
__launch_bounds__(256, 2)
__global__ void mlp_gemm(const unsigned short* __restrict__ Abase,
                         const unsigned short* __restrict__ Wt,
                         const float* __restrict__ bias,
                         unsigned short* __restrict__ Hout,
                         float* __restrict__ Out,
                         const int* __restrict__ cnt,
                         const int* __restrict__ rowlist) {
  constexpr int N  = (LAYER == 3) ? NC : NH;
  constexpr int K  = (LAYER == 1) ? KP1 : NH;
  constexpr int BM = 128;
  constexpr int BN = (LAYER == 3) ? 64 : 128;
  constexpr int NB = (LAYER == 3) ? 1 : (NH / 128);
  constexpr int NKT = K / 64;
  constexpr int MF = (LAYER == 3) ? 2 : 4;
  constexpr int BI = (LAYER == 3) ? 2 : 4;

  const int wg = xcd_chunk(blockIdx.x, MTILES * NB);
  const int ty = wg / NB;
  const int n0 = (wg % NB) * BN;

  int f = -1, m0 = 0, goff = 0, cntf = 0;
  {
    int acc = 0, off = 0;
#pragma unroll
    for (int i = 0; i < NFAC; ++i) {
      int c = cnt[i];
      int t = (c + BM - 1) >> 7;
      if (f < 0 && ty < acc + t) { f = i; m0 = (ty - acc) * BM; goff = off; cntf = c; }
      acc += t; off += c;
    }
  }
  if (f < 0) return;

  __shared__ unsigned short As[2][BM * 64];
  __shared__ unsigned short Bs[2][BN * 64];

  const int tid = threadIdx.x;
  const int wid = tid >> 6, lane = tid & 63;
  const int wm = (LAYER == 3) ? wid : (wid >> 1);
  const int wn = (LAYER == 3) ? 0 : (wid & 1);

  const int rl = lane >> 3;
  const int chs = (lane & 7) ^ rl;
  const unsigned short* pA[4];
  const unsigned short* pB[BI];
  {
    const unsigned short* Aorg = Abase + (size_t)(goff + m0) * K;
    const unsigned short* Borg = Wt + (size_t)f * N * K + (size_t)n0 * K;
#pragma unroll
    for (int i = 0; i < 4; ++i)
      pA[i] = Aorg + (size_t)(wid * 32 + i * 8 + rl) * K + chs * 8;
#pragma unroll
    for (int i = 0; i < BI; ++i)
      pB[i] = Borg + (size_t)(wid * (8 * BI) + i * 8 + rl) * K + chs * 8;
  }

  f32x4 acc[MF][4];
#pragma unroll
  for (int a = 0; a < MF; ++a)
#pragma unroll
    for (int b = 0; b < 4; ++b) acc[a][b] = (f32x4){0.f, 0.f, 0.f, 0.f};

  auto stage = [&](int buf) {
#pragma unroll
    for (int i = 0; i < 4; ++i) {
      gl_lds16(pA[i], &As[buf][(wid * 32 + i * 8) * 64]);
      pA[i] += 64;
    }
#pragma unroll
    for (int i = 0; i < BI; ++i) {
      gl_lds16(pB[i], &Bs[buf][(wid * (8 * BI) + i * 8) * 64]);
      pB[i] += 64;
    }
  };

  auto compute = [&](int buf) {
#pragma unroll
    for (int ks = 0; ks < 2; ++ks) {
      const int kc8 = ks * 4 + (lane >> 4);
      short8 av[MF], bv[4];
#pragma unroll
      for (int mf = 0; mf < MF; ++mf) {
        int row = wm * (MF * 16) + mf * 16 + (lane & 15);
        av[mf] = *(const short8*)(&As[buf][0] + row * 64 + ((kc8 ^ (row & 7)) << 3));
      }
#pragma unroll
      for (int nf = 0; nf < 4; ++nf) {
        int col = wn * 64 + nf * 16 + (lane & 15);
        bv[nf] = *(const short8*)(&Bs[buf][0] + col * 64 + ((kc8 ^ (col & 7)) << 3));
      }
      __builtin_amdgcn_s_setprio(1);
#pragma unroll
      for (int mf = 0; mf < MF; ++mf)
#pragma unroll
        for (int nf = 0; nf < 4; ++nf)
          acc[mf][nf] = __builtin_amdgcn_mfma_f32_16x16x32_bf16(
              av[mf], bv[nf], acc[mf][nf], 0, 0, 0);
      __builtin_amdgcn_s_setprio(0);
    }
  };

  stage(0);
  stage(1);
#pragma unroll 1
  for (int kt = 0; kt < NKT; ++kt) {
    if (kt < NKT - 1) {
      if constexpr (LAYER == 3)
        asm volatile("s_waitcnt vmcnt(6)" ::: "memory");
      else
        asm volatile("s_waitcnt vmcnt(8)" ::: "memory");
    } else {
      asm volatile("s_waitcnt vmcnt(0)" ::: "memory");
    }
    __builtin_amdgcn_sched_barrier(0);
    __builtin_amdgcn_s_barrier();
    __builtin_amdgcn_sched_barrier(0);
    compute(kt & 1);
    __builtin_amdgcn_sched_barrier(0);
    __builtin_amdgcn_s_barrier();
    __builtin_amdgcn_sched_barrier(0);
    if (kt + 2 < NKT) stage(kt & 1);
  }

  if (LAYER == 3) {
    const float* bs = bias + f * NC;
#pragma unroll
    for (int nf = 0; nf < 4; ++nf) {
      int col = nf * 16 + (lane & 15);
      float bv = bs[col];
#pragma unroll
      for (int mf = 0; mf < MF; ++mf) {
        int rbase = wm * (MF * 16) + mf * 16 + ((lane >> 4) << 2);
#pragma unroll
        for (int i = 0; i < 4; ++i) {
          int pos = m0 + rbase + i;
          if (pos < cntf) {
            int b = rowlist[f * BB + pos];
            Out[(size_t)b * NC + col] = acc[mf][nf][i] + bv;
          }
        }
      }
    }
  } else {
    const float* bs = bias + f * NH;
#pragma unroll
    for (int nf = 0; nf < 4; ++nf) {
      int col = n0 + wn * 64 + nf * 16 + (lane & 15);
      float bv = bs[col];
#pragma unroll
      for (int mf = 0; mf < MF; ++mf) {
        int rbase = wm * (MF * 16) + mf * 16 + ((lane >> 4) << 2);
#pragma unroll
        for (int i = 0; i < 4; ++i) {
          int pos = m0 + rbase + i;
          if (pos < cntf) {
            float v = fmaxf(acc[mf][nf][i] + bv, 0.0f);
            Hout[(size_t)(goff + pos) * NH + col] = f2bf(v);
          }
        }
      }
    }
  }
}

extern "C" void kernel_launch(void* const* d_in, const int* in_sizes, int n_in,
                              void* d_out, int out_size, void* d_ws, size_t ws_size,
                              hipStream_t stream) {
  const float* graph = (const float*)d_in[0];
  const float* state = (const float*)d_in[1];
  const float* nexts = (const float*)d_in[2];
  const float* W1 = (const float*)d_in[3];
  const float* b1 = (const float*)d_in[4];
  const float* W2 = (const float*)d_in[5];
  const float* b2 = (const float*)d_in[6];
  const float* W3 = (const float*)d_in[7];
  const float* b3 = (const float*)d_in[8];
  float* out = (float*)d_out;
  char* ws = (char*)d_ws;

  const size_t ROWCAP = BB + 256;  // +256 rows: 256-tile staging pad
  const size_t OFF_ROW = 256;
  const size_t OFF_W1T = OFF_ROW + (size_t)NFAC * BB * 4;
  const size_t OFF_W2T = OFF_W1T + (size_t)NFAC * NH * KP1 * 2;
  const size_t OFF_W3T = OFF_W2T + (size_t)NFAC * NH * NH * 2;
  const size_t OFF_H1  = OFF_W3T + (size_t)NFAC * NC * NH * 2;
  const size_t OFF_XG  = OFF_H1 + ROWCAP * NH * 2;

  int* cnt = (int*)ws;
  int* rowlist = (int*)(ws + OFF_ROW);
  unsigned short* w1t = (unsigned short*)(ws + OFF_W1T);
  unsigned short* w2t = (unsigned short*)(ws + OFF_W2T);
  unsigned short* w3t = (unsigned short*)(ws + OFF_W3T);
  unsigned short* h1  = (unsigned short*)(ws + OFF_H1);
  unsigned short* xg  = (unsigned short*)(ws + OFF_XG);
  unsigned short* h2  = xg;  // reuse: xg dead after layer 1

  hipFuncSetAttribute(reinterpret_cast<const void*>(mlp_gemm256<1>),
                      hipFuncAttributeMaxDynamicSharedMemorySize, 131072);
  hipFuncSetAttribute(reinterpret_cast<const void*>(mlp_gemm256<2>),
                      hipFuncAttributeMaxDynamicSharedMemorySize, 131072);

  hipMemsetAsync(cnt, 0, 64, stream);
  hipMemsetAsync(d_out, 0, (size_t)out_size * sizeof(float), stream);

  bucket_kernel<<<BB / 256, 256, 0, stream>>>(graph, cnt, rowlist);
  gather_x<<<BB / 4, 256, 0, stream>>>(graph, state, nexts, cnt, rowlist, xg);
  transpose_all<<<dim3(16, 20, 24), 256, 0, stream>>>(W1, W2, W3, w1t, w2t, w3t);

  mlp_gemm256<1><<<MT256 * 4, 512, 131072, stream>>>(xg, w1t, b1, h1, cnt);
  mlp_gemm256<2><<<MT256 * 4, 512, 131072, stream>>>(h1, w2t, b2, h2, cnt);
  mlp_gemm<3><<<MTILES, 256, 0, stream>>>(h2, w3t, b3, nullptr, out, cnt, rowlist);
}

// Round 10
// 243.166 us; speedup vs baseline: 1.1107x; 1.1107x over previous
//
#include <hip/hip_runtime.h>

#define BB   16384
#define GENC 216
#define OBS  512
#define NH   1024
#define NC   64
#define NFAC 8
#define NIN  1240
#define KP1  1280   // layer-1 K padded to multiple of 64
#define MTILES 136  // worst-case sum ceil(cnt_f/128)

typedef __attribute__((ext_vector_type(4))) float f32x4;
typedef __attribute__((ext_vector_type(8))) short short8;
typedef __attribute__((ext_vector_type(4))) short short4v;

__device__ __forceinline__ unsigned short f2bf(float f) {
  union { float f; unsigned u; } x; x.f = f;
  unsigned r = x.u + 0x7fffu + ((x.u >> 16) & 1u);
  return (unsigned short)(r >> 16);
}

__device__ __forceinline__ void gl_lds16(const unsigned short* g, unsigned short* l) {
  __builtin_amdgcn_global_load_lds(
      (const __attribute__((address_space(1))) void*)g,
      (__attribute__((address_space(3))) void*)l, 16, 0, 0);
}

// bijective XCD-chunked swizzle (m204)
__device__ __forceinline__ int xcd_chunk(int gid, int nwg) {
  int q = nwg >> 3, r = nwg & 7, x = gid & 7, p = gid >> 3;
  return (x < r ? x * (q + 1) : r * (q + 1) + (x - r) * q) + p;
}

// ---------- bucket: per-row last-active factor, LDS-aggregated atomics ----------
__global__ void bucket_kernel(const float* __restrict__ graph,
                              int* __restrict__ cnt, int* __restrict__ rowlist) {
  __shared__ int lcnt[NFAC];
  __shared__ int lbase[NFAC];
  int tid = threadIdx.x;
  if (tid < NFAC) lcnt[tid] = 0;
  __syncthreads();
  int b = blockIdx.x * 256 + tid;
  const float* g = graph + (size_t)b * GENC;
  float4 g0 = *(const float4*)g;
  float4 g1 = *(const float4*)(g + 4);
  int f = -1;
  if (g0.x == 1.f) f = 0;
  if (g0.y == 1.f) f = 1;
  if (g0.z == 1.f) f = 2;
  if (g0.w == 1.f) f = 3;
  if (g1.x == 1.f) f = 4;
  if (g1.y == 1.f) f = 5;
  if (g1.z == 1.f) f = 6;
  if (g1.w == 1.f) f = 7;
  int li = 0;
  if (f >= 0) li = atomicAdd(&lcnt[f], 1);
  __syncthreads();
  if (tid < NFAC) lbase[tid] = lcnt[tid] ? atomicAdd(&cnt[tid], lcnt[tid]) : 0;
  __syncthreads();
  if (f >= 0) rowlist[f * BB + lbase[f] + li] = b;
}

// -------- gather active rows (global position), concat + f32->bf16, pad to 1280 --------
__global__ void gather_x(const float* __restrict__ graph,
                         const float* __restrict__ state,
                         const float* __restrict__ nexts,
                         const int* __restrict__ cnt,
                         const int* __restrict__ rowlist,
                         unsigned short* __restrict__ xg) {
  int w = threadIdx.x >> 6, lane = threadIdx.x & 63;
  int pos = blockIdx.x * 4 + w;
  int f = -1, loc = 0, acc = 0;
#pragma unroll
  for (int i = 0; i < NFAC; ++i) {
    int c = cnt[i];
    if (f < 0 && pos < acc + c) { f = i; loc = pos - acc; }
    acc += c;
  }
  if (f < 0) return;
  int b = rowlist[f * BB + loc];
  unsigned short* dst = xg + (size_t)pos * KP1;
#pragma unroll
  for (int it = 0; it < 5; ++it) {
    int c = it * 64 + lane;
    float4 v;
    if (c < 54)       v = *(const float4*)(graph + (size_t)b * GENC + c * 4);
    else if (c < 182) v = *(const float4*)(state + (size_t)b * OBS + (c - 54) * 4);
    else if (c < 310) v = *(const float4*)(nexts + (size_t)b * OBS + (c - 182) * 4);
    else              v = make_float4(0.f, 0.f, 0.f, 0.f);
    short4v s;
    s[0] = (short)f2bf(v.x); s[1] = (short)f2bf(v.y);
    s[2] = (short)f2bf(v.z); s[3] = (short)f2bf(v.w);
    *(short4v*)(dst + c * 4) = s;
  }
}

// ---- merged transpose+convert: f32 [F][K][N] -> bf16 [F][N][KPad] ----
__global__ void transpose_all(const float* __restrict__ W1,
                              const float* __restrict__ W2,
                              const float* __restrict__ W3,
                              unsigned short* __restrict__ w1t,
                              unsigned short* __restrict__ w2t,
                              unsigned short* __restrict__ w3t) {
  __shared__ unsigned short tile[64][65];
  int z = blockIdx.z;
  const float* src; unsigned short* dst; int K, N, KPad;
  if (z < 8)        { src = W1 + (size_t)z * NIN * NH;       dst = w1t + (size_t)z * NH * KP1; K = NIN; N = NH; KPad = KP1; }
  else if (z < 16)  { src = W2 + (size_t)(z - 8) * NH * NH;  dst = w2t + (size_t)(z - 8) * NH * NH; K = NH; N = NH; KPad = NH; }
  else              { src = W3 + (size_t)(z - 16) * NH * NC; dst = w3t + (size_t)(z - 16) * NC * NH; K = NH; N = NC; KPad = NH; }
  int k0 = blockIdx.y * 64, n0 = blockIdx.x * 64;
  if (k0 >= KPad || n0 >= N) return;
  int tr = threadIdx.x >> 6, tc = threadIdx.x & 63;
#pragma unroll
  for (int i = 0; i < 16; ++i) {
    int r = i * 4 + tr;
    int k = k0 + r;
    float v = (k < K) ? src[(size_t)k * N + n0 + tc] : 0.0f;
    tile[r][tc] = f2bf(v);
  }
  __syncthreads();
  int kp = threadIdx.x & 31, nb = threadIdx.x >> 5;
#pragma unroll
  for (int i = 0; i < 8; ++i) {
    int n = i * 8 + nb;
    union { short2 s2; unsigned u; } v;
    v.s2.x = (short)tile[kp * 2][n];
    v.s2.y = (short)tile[kp * 2 + 1][n];
    *(unsigned*)(dst + (size_t)(n0 + n) * KPad + k0 + kp * 2) = v.u;
  }
}

// ====== L1/L2 GEMM: 128x256 tile, 8 waves, TRIPLE-buffered counted-vmcnt ======
// Per K-tile: 6 staging units of 8KB (A rows 0-63,64-127; B cols 4x64).
// Lookahead = 2 tiles (stage t+2 while computing t); one barrier per tile;
// steady-state wait vmcnt(6) leaves tile t+1's 6 loads in flight.
template <int LAYER>
__launch_bounds__(512, 2)
__global__ void mlp_gemm_big(const unsigned short* __restrict__ Abase,
                             const unsigned short* __restrict__ Wt,
                             const float* __restrict__ bias,
                             unsigned short* __restrict__ Hout,
                             const int* __restrict__ cnt) {
  constexpr int K  = (LAYER == 1) ? KP1 : NH;
  constexpr int NT = K / 64;
  constexpr int NB = NH / 256;  // 4 n-blocks

  extern __shared__ unsigned short smem[];

  const int wg = xcd_chunk(blockIdx.x, MTILES * NB);
  const int ty = wg / NB;           // m-tile; n fastest (A-panel L2 reuse)
  const int n0 = (wg % NB) * 256;

  int f = -1, m0 = 0, goff = 0, cntf = 0;
  {
    int acc = 0, off = 0;
#pragma unroll
    for (int i = 0; i < NFAC; ++i) {
      int c = cnt[i];
      int t = (c + 127) >> 7;
      if (f < 0 && ty < acc + t) { f = i; m0 = (ty - acc) * 128; goff = off; cntf = c; }
      acc += t; off += c;
    }
  }
  if (f < 0) return;

  const int tid = threadIdx.x, wid = tid >> 6, lane = tid & 63;
  const int wm = wid >> 2, wn = wid & 3;   // 2m x 4n waves, 64x64 out each

  // staging: per-lane pre-swizzled source, linear LDS dest (rule 21)
  const int sr = tid >> 3;              // row within 64-row unit
  const int sc = (tid & 7) ^ (sr & 7);  // swizzled 16B chunk
  const unsigned short* pu[6];
  {
    const unsigned short* Ao = Abase + (size_t)(goff + m0) * K;
    const unsigned short* Bo = Wt + (size_t)f * NH * K + (size_t)n0 * K;
    pu[0] = Ao + (size_t)sr * K + sc * 8;
    pu[1] = Ao + (size_t)(64 + sr) * K + sc * 8;
#pragma unroll
    for (int u = 0; u < 4; ++u) pu[2 + u] = Bo + (size_t)(u * 64 + sr) * K + sc * 8;
  }
  const int dst8 = tid * 8;  // linear elem offset within a unit

  // 3 buffers of A(8192)+B(16384) elems
  unsigned short* A0 = smem;              unsigned short* B0 = smem + 8192;
  unsigned short* A1 = smem + 24576;      unsigned short* B1 = A1 + 8192;
  unsigned short* A2 = smem + 49152;      unsigned short* B2 = A2 + 8192;

  f32x4 acc[4][4];
#pragma unroll
  for (int a = 0; a < 4; ++a)
#pragma unroll
    for (int b = 0; b < 4; ++b) acc[a][b] = (f32x4){0.f, 0.f, 0.f, 0.f};

  auto stage = [&](unsigned short* Ab, unsigned short* Bb) {
    gl_lds16(pu[0], Ab + dst8);        pu[0] += 64;
    gl_lds16(pu[1], Ab + 4096 + dst8); pu[1] += 64;
#pragma unroll
    for (int u = 0; u < 4; ++u) { gl_lds16(pu[2 + u], Bb + u * 4096 + dst8); pu[2 + u] += 64; }
  };

  // prologue: tiles 0,1 in flight (12 loads/thread)
  stage(A0, B0);
  stage(A1, B1);
  unsigned short *Ac = A0, *Bc = B0, *An = A1, *Bn = B1, *Af = A2, *Bf = B2;

#pragma unroll 1
  for (int t = 0; t < NT; ++t) {
    if (t < NT - 1) { asm volatile("s_waitcnt vmcnt(6)" ::: "memory"); }
    else            { asm volatile("s_waitcnt vmcnt(0)" ::: "memory"); }
    __builtin_amdgcn_sched_barrier(0);
    __builtin_amdgcn_s_barrier();      // tile t resident; buf freed at t-1 reusable
    __builtin_amdgcn_sched_barrier(0);

    short8 av[4][2], bv[4][2];
#pragma unroll
    for (int nf = 0; nf < 4; ++nf) {
      int c = wn * 64 + nf * 16 + (lane & 15);
#pragma unroll
      for (int ks = 0; ks < 2; ++ks) {
        int kc = ks * 4 + (lane >> 4);
        bv[nf][ks] = *(const short8*)(Bc + c * 64 + ((kc ^ (c & 7)) << 3));
      }
    }
#pragma unroll
    for (int mf = 0; mf < 4; ++mf) {
      int r = wm * 64 + mf * 16 + (lane & 15);
#pragma unroll
      for (int ks = 0; ks < 2; ++ks) {
        int kc = ks * 4 + (lane >> 4);
        av[mf][ks] = *(const short8*)(Ac + r * 64 + ((kc ^ (r & 7)) << 3));
      }
    }
    if (t + 2 < NT) stage(Af, Bf);     // refill the freed buffer with tile t+2
    __builtin_amdgcn_s_setprio(1);
#pragma unroll
    for (int mf = 0; mf < 4; ++mf)
#pragma unroll
      for (int nf = 0; nf < 4; ++nf)
#pragma unroll
        for (int ks = 0; ks < 2; ++ks)
          acc[mf][nf] = __builtin_amdgcn_mfma_f32_16x16x32_bf16(
              av[mf][ks], bv[nf][ks], acc[mf][nf], 0, 0, 0);
    __builtin_amdgcn_s_setprio(0);
    // rotate buffers (static-named: no dynamic indexing)
    unsigned short* ta = Ac; unsigned short* tb = Bc;
    Ac = An; Bc = Bn; An = Af; Bn = Bf; Af = ta; Bf = tb;
  }

  // ---- epilogue: bias + relu + bf16 store ----
  const float* bs = bias + f * NH;
#pragma unroll
  for (int nf = 0; nf < 4; ++nf) {
    int col = n0 + wn * 64 + nf * 16 + (lane & 15);
    float bvv = bs[col];
#pragma unroll
    for (int mf = 0; mf < 4; ++mf) {
      int rbase = wm * 64 + mf * 16 + ((lane >> 4) << 2);
#pragma unroll
      for (int i = 0; i < 4; ++i) {
        int pos = m0 + rbase + i;
        if (pos < cntf) {
          float v = fmaxf(acc[mf][nf][i] + bvv, 0.0f);
          Hout[(size_t)(goff + pos) * NH + col] = f2bf(v);
        }
      }
    }
  }
}

// ------ layer-3 GEMM: depth-2 counted-vmcnt 128x64 (rowlist scatter epilogue) ------
__launch_bounds__(256, 2)
__global__ void mlp_gemm3(const unsigned short* __restrict__ Abase,
                          const unsigned short* __restrict__ Wt,
                          const float* __restrict__ bias,
                          float* __restrict__ Out,
                          const int* __restrict__ cnt,
                          const int* __restrict__ rowlist) {
  constexpr int K = NH;
  constexpr int NKT = K / 64;

  const int wg = xcd_chunk(blockIdx.x, MTILES);
  const int ty = wg;

  int f = -1, m0 = 0, goff = 0, cntf = 0;
  {
    int acc = 0, off = 0;
#pragma unroll
    for (int i = 0; i < NFAC; ++i) {
      int c = cnt[i];
      int t = (c + 127) >> 7;
      if (f < 0 && ty < acc + t) { f = i; m0 = (ty - acc) * 128; goff = off; cntf = c; }
      acc += t; off += c;
    }
  }
  if (f < 0) return;

  __shared__ unsigned short As[2][128 * 64];
  __shared__ unsigned short Bs[2][64 * 64];

  const int tid = threadIdx.x;
  const int wid = tid >> 6, lane = tid & 63;

  const int rl = lane >> 3;
  const int chs = (lane & 7) ^ rl;
  const unsigned short* pA[4];
  const unsigned short* pB[2];
  {
    const unsigned short* Aorg = Abase + (size_t)(goff + m0) * K;
    const unsigned short* Borg = Wt + (size_t)f * NC * K;
#pragma unroll
    for (int i = 0; i < 4; ++i)
      pA[i] = Aorg + (size_t)(wid * 32 + i * 8 + rl) * K + chs * 8;
#pragma unroll
    for (int i = 0; i < 2; ++i)
      pB[i] = Borg + (size_t)(wid * 16 + i * 8 + rl) * K + chs * 8;
  }

  f32x4 acc[2][4];
#pragma unroll
  for (int a = 0; a < 2; ++a)
#pragma unroll
    for (int b = 0; b < 4; ++b) acc[a][b] = (f32x4){0.f, 0.f, 0.f, 0.f};

  auto stage = [&](int buf) {
#pragma unroll
    for (int i = 0; i < 4; ++i) {
      gl_lds16(pA[i], &As[buf][(wid * 32 + i * 8) * 64]);
      pA[i] += 64;
    }
#pragma unroll
    for (int i = 0; i < 2; ++i) {
      gl_lds16(pB[i], &Bs[buf][(wid * 16 + i * 8) * 64]);
      pB[i] += 64;
    }
  };

  auto compute = [&](int buf) {
#pragma unroll
    for (int ks = 0; ks < 2; ++ks) {
      const int kc8 = ks * 4 + (lane >> 4);
      short8 av[2], bv[4];
#pragma unroll
      for (int mf = 0; mf < 2; ++mf) {
        int row = wid * 32 + mf * 16 + (lane & 15);
        av[mf] = *(const short8*)(&As[buf][0] + row * 64 + ((kc8 ^ (row & 7)) << 3));
      }
#pragma unroll
      for (int nf = 0; nf < 4; ++nf) {
        int col = nf * 16 + (lane & 15);
        bv[nf] = *(const short8*)(&Bs[buf][0] + col * 64 + ((kc8 ^ (col & 7)) << 3));
      }
      __builtin_amdgcn_s_setprio(1);
#pragma unroll
      for (int mf = 0; mf < 2; ++mf)
#pragma unroll
        for (int nf = 0; nf < 4; ++nf)
          acc[mf][nf] = __builtin_amdgcn_mfma_f32_16x16x32_bf16(
              av[mf], bv[nf], acc[mf][nf], 0, 0, 0);
      __builtin_amdgcn_s_setprio(0);
    }
  };

  stage(0);
  stage(1);
#pragma unroll 1
  for (int kt = 0; kt < NKT; ++kt) {
    if (kt < NKT - 1) { asm volatile("s_waitcnt vmcnt(6)" ::: "memory"); }
    else              { asm volatile("s_waitcnt vmcnt(0)" ::: "memory"); }
    __builtin_amdgcn_sched_barrier(0);
    __builtin_amdgcn_s_barrier();
    __builtin_amdgcn_sched_barrier(0);
    compute(kt & 1);
    __builtin_amdgcn_sched_barrier(0);
    __builtin_amdgcn_s_barrier();
    __builtin_amdgcn_sched_barrier(0);
    if (kt + 2 < NKT) stage(kt & 1);
  }

  const float* bs = bias + f * NC;
#pragma unroll
  for (int nf = 0; nf < 4; ++nf) {
    int col = nf * 16 + (lane & 15);
    float bvv = bs[col];
#pragma unroll
    for (int mf = 0; mf < 2; ++mf) {
      int rbase = wid * 32 + mf * 16 + ((lane >> 4) << 2);
#pragma unroll
      for (int i = 0; i < 4; ++i) {
        int pos = m0 + rbase + i;
        if (pos < cntf) {
          int b = rowlist[f * BB + pos];
          Out[(size_t)b * NC + col] = acc[mf][nf][i] + bvv;
        }
      }
    }
  }
}

extern "C" void kernel_launch(void* const* d_in, const int* in_sizes, int n_in,
                              void* d_out, int out_size, void* d_ws, size_t ws_size,
                              hipStream_t stream) {
  const float* graph = (const float*)d_in[0];
  const float* state = (const float*)d_in[1];
  const float* nexts = (const float*)d_in[2];
  const float* W1 = (const float*)d_in[3];
  const float* b1 = (const float*)d_in[4];
  const float* W2 = (const float*)d_in[5];
  const float* b2 = (const float*)d_in[6];
  const float* W3 = (const float*)d_in[7];
  const float* b3 = (const float*)d_in[8];
  float* out = (float*)d_out;
  char* ws = (char*)d_ws;

  const size_t ROWCAP = BB + 256;
  const size_t OFF_ROW = 256;
  const size_t OFF_W1T = OFF_ROW + (size_t)NFAC * BB * 4;
  const size_t OFF_W2T = OFF_W1T + (size_t)NFAC * NH * KP1 * 2;
  const size_t OFF_W3T = OFF_W2T + (size_t)NFAC * NH * NH * 2;
  const size_t OFF_H1  = OFF_W3T + (size_t)NFAC * NC * NH * 2;
  const size_t OFF_XG  = OFF_H1 + ROWCAP * NH * 2;

  int* cnt = (int*)ws;
  int* rowlist = (int*)(ws + OFF_ROW);
  unsigned short* w1t = (unsigned short*)(ws + OFF_W1T);
  unsigned short* w2t = (unsigned short*)(ws + OFF_W2T);
  unsigned short* w3t = (unsigned short*)(ws + OFF_W3T);
  unsigned short* h1  = (unsigned short*)(ws + OFF_H1);
  unsigned short* xg  = (unsigned short*)(ws + OFF_XG);
  unsigned short* h2  = xg;  // reuse: xg dead after layer 1

  hipFuncSetAttribute(reinterpret_cast<const void*>(mlp_gemm_big<1>),
                      hipFuncAttributeMaxDynamicSharedMemorySize, 147456);
  hipFuncSetAttribute(reinterpret_cast<const void*>(mlp_gemm_big<2>),
                      hipFuncAttributeMaxDynamicSharedMemorySize, 147456);

  hipMemsetAsync(cnt, 0, 64, stream);
  hipMemsetAsync(d_out, 0, (size_t)out_size * sizeof(float), stream);

  bucket_kernel<<<BB / 256, 256, 0, stream>>>(graph, cnt, rowlist);
  gather_x<<<BB / 4, 256, 0, stream>>>(graph, state, nexts, cnt, rowlist, xg);
  transpose_all<<<dim3(16, 20, 24), 256, 0, stream>>>(W1, W2, W3, w1t, w2t, w3t);

  mlp_gemm_big<1><<<MTILES * 4, 512, 147456, stream>>>(xg, w1t, b1, h1, cnt);
  mlp_gemm_big<2><<<MTILES * 4, 512, 147456, stream>>>(h1, w2t, b2, h2, cnt);
  mlp_gemm3<<<MTILES, 256, 0, stream>>>(h2, w3t, b3, out, cnt, rowlist);
}